// Round 2
// baseline (352.484 us; speedup 1.0000x reference)
//
#include <hip/hip_runtime.h>
#include <math.h>

// ChannelDropout: out[b,c,t] = sig[b,c,t] * kept[b,c] / (1e-8 + proba[b,c])
//   kept[b,c]  = ||pos[b,c] - center|| > 0.2
//   proba[b,c] = mean_i( ||pos[b,c] - mc[i]|| > 0.2 ), i in [0,100)
//
// Two kernels:
//  1) scale_kernel: one thread per (b,c) channel -> scale[row] into d_ws.
//     MC centers staged in LDS; ~17472 threads total, a few microseconds.
//  2) stream_kernel: one block per 4 contiguous rows, pure float4 streaming
//     multiply with nontemporal hints (419 MB total traffic, zero reuse).
//     No __syncthreads in the streaming path; ~12 iters/thread for MLP.

typedef float vfloat4 __attribute__((ext_vector_type(4)));

__global__ __launch_bounds__(256) void scale_kernel(
    const float* __restrict__ pos,      // (rows, 2)
    const float* __restrict__ center,   // (2,)
    const float* __restrict__ mc,       // (NMC, 2)
    float* __restrict__ scales,         // (rows,)
    int rows, int NMC)
{
    extern __shared__ float s_mc[];     // 2*NMC floats
    for (int i = threadIdx.x; i < 2 * NMC; i += blockDim.x)
        s_mc[i] = mc[i];
    __syncthreads();

    const int row = blockIdx.x * blockDim.x + threadIdx.x;
    if (row >= rows) return;

    const float px = pos[2 * row + 0];
    const float py = pos[2 * row + 1];

    float cnt = 0.0f;
    for (int j = 0; j < NMC; ++j) {
        const float dx = px - s_mc[2 * j + 0];
        const float dy = py - s_mc[2 * j + 1];
        cnt += (sqrtf(dx * dx + dy * dy) > 0.2f) ? 1.0f : 0.0f;
    }
    const float proba = cnt / (float)NMC;

    const float dx = px - center[0];
    const float dy = py - center[1];
    const float kept = (sqrtf(dx * dx + dy * dy) > 0.2f) ? 1.0f : 0.0f;

    scales[row] = kept / (1e-8f + proba);
}

// ROWS_PER_BLOCK contiguous rows per block: flat float4 streaming since rows
// are contiguous in memory; only the scale selection needs the row index.
#define ROWS_PER_BLOCK 4

__global__ __launch_bounds__(256) void stream_kernel(
    const float* __restrict__ sig,
    const float* __restrict__ scales,
    float* __restrict__ out,
    int n4_per_row,                     // T/4 (=750)
    int rows)
{
    const int r0 = blockIdx.x * ROWS_PER_BLOCK;
    const int nr = min(ROWS_PER_BLOCK, rows - r0);

    float s0 = scales[r0];
    float s1 = (nr > 1) ? scales[r0 + 1] : 0.0f;
    float s2 = (nr > 2) ? scales[r0 + 2] : 0.0f;
    float s3 = (nr > 3) ? scales[r0 + 3] : 0.0f;

    const size_t base4 = (size_t)r0 * (size_t)n4_per_row;
    const int total4 = nr * n4_per_row;
    const int n1 = n4_per_row, n2 = 2 * n4_per_row, n3 = 3 * n4_per_row;

    const vfloat4* __restrict__ in4 = (const vfloat4*)sig + base4;
    vfloat4* __restrict__ out4 = (vfloat4*)out + base4;

    for (int i = threadIdx.x; i < total4; i += 256) {
        const float sc = (i < n1) ? s0 : (i < n2) ? s1 : (i < n3) ? s2 : s3;
        vfloat4 v = __builtin_nontemporal_load(in4 + i);
        v *= sc;
        __builtin_nontemporal_store(v, out4 + i);
    }
}

// Scalar tail kernel in case T % 4 != 0 (not hit for T=3000).
__global__ __launch_bounds__(256) void tail_kernel(
    const float* __restrict__ sig,
    const float* __restrict__ scales,
    float* __restrict__ out,
    int T, int tail_start, int rows)
{
    const int row = blockIdx.x;
    const float sc = scales[row];
    const size_t base = (size_t)row * (size_t)T;
    for (int i = tail_start + (int)threadIdx.x; i < T; i += blockDim.x)
        out[base + i] = sig[base + i] * sc;
}

extern "C" void kernel_launch(void* const* d_in, const int* in_sizes, int n_in,
                              void* d_out, int out_size, void* d_ws, size_t ws_size,
                              hipStream_t stream) {
    const float* sig    = (const float*)d_in[0];  // (B, C, T) f32
    const float* pos    = (const float*)d_in[1];  // (B, C, 2) f32
    const float* center = (const float*)d_in[2];  // (2,)      f32
    const float* mc     = (const float*)d_in[3];  // (N, 2)    f32
    float* out          = (float*)d_out;          // (B, C, T) f32
    float* scales       = (float*)d_ws;           // rows floats (70 KB)

    const int rows = in_sizes[1] / 2;             // B*C = 17472
    const int T    = in_sizes[0] / rows;          // 3000
    const int NMC  = in_sizes[3] / 2;             // 100

    // 1) per-channel scales
    {
        const int blocks = (rows + 255) / 256;
        const size_t lds = (size_t)(2 * NMC) * sizeof(float);
        scale_kernel<<<blocks, 256, lds, stream>>>(pos, center, mc, scales,
                                                   rows, NMC);
    }

    // 2) streaming multiply
    {
        const int n4 = T / 4;                     // float4 per row
        const int blocks = (rows + ROWS_PER_BLOCK - 1) / ROWS_PER_BLOCK;
        stream_kernel<<<blocks, 256, 0, stream>>>(sig, scales, out, n4, rows);
        if (T % 4 != 0) {
            tail_kernel<<<rows, 64, 0, stream>>>(sig, scales, out, T, n4 * 4,
                                                 rows);
        }
    }
}